// Round 1
// baseline (1620.063 us; speedup 1.0000x reference)
//
#include <hip/hip_runtime.h>

#define N_NODES 500000
#define N_EDGES 8000000

__device__ __constant__ float kEPS = 1e-8f;

struct Accum {
    double pde_sum;
    double bc_sum;
    double bc_cnt;
    double j1_sum;
    double j2_sum;
    double het_cnt;
};

// Block-wide f64 sum. Valid result on thread 0 only.
__device__ double block_reduce(double v) {
    __shared__ double sm[16];
    __syncthreads();                       // guard shared reuse across calls
    for (int off = 32; off; off >>= 1) v += __shfl_down(v, off, 64);
    const int lane = threadIdx.x & 63, wid = threadIdx.x >> 6;
    if (lane == 0) sm[wid] = v;
    __syncthreads();
    if (wid == 0) {
        const int nw = blockDim.x >> 6;
        v = (lane < nw) ? sm[lane] : 0.0;
        for (int off = 8; off; off >>= 1) v += __shfl_down(v, off, 64);
    }
    return v;
}

// Pass 1 over edges: scatter segment sums dx/dy/lap (atomic), j1 loss, het count.
__global__ void edge_pass1(const float* __restrict__ u_pred,
                           const float* __restrict__ x,
                           const float* __restrict__ j1,
                           const float* __restrict__ cdx,
                           const float* __restrict__ cdy,
                           const float* __restrict__ clap,
                           const int* __restrict__ row_idx,
                           const int* __restrict__ col_idx,
                           const int* __restrict__ eattr,
                           float* __restrict__ dx,
                           float* __restrict__ dy,
                           float* __restrict__ lap,
                           Accum* __restrict__ acc) {
    double j1s = 0.0, hc = 0.0;
    const int stride = gridDim.x * blockDim.x;
    for (int e = blockIdx.x * blockDim.x + threadIdx.x; e < N_EDGES; e += stride) {
        const int r = row_idx[e];
        const int c = col_idx[e];
        const float ud = u_pred[c] - u_pred[r];
        atomicAdd(&dx[r],  ud * cdx[e]);
        atomicAdd(&dy[r],  ud * cdy[e]);
        atomicAdd(&lap[r], ud * clap[e]);
        if (eattr[e] == 1) {
            const float z   = x[4 * c + 3];
            const float sgn = (float)(z > 0.0f) - (float)(z < 0.0f);
            const float d   = sgn * ud - j1[r];
            j1s += (double)(d * d);
            hc  += 1.0;
        }
    }
    double t = block_reduce(j1s);
    if (threadIdx.x == 0) atomicAdd(&acc->j1_sum, t);
    t = block_reduce(hc);
    if (threadIdx.x == 0) atomicAdd(&acc->het_cnt, t);
}

// Node pass: PDE residual + boundary loss.
__global__ void node_pass(const float* __restrict__ u_pred,
                          const float* __restrict__ x,
                          const float* __restrict__ pos,
                          const float* __restrict__ y,
                          const float* __restrict__ source,
                          const float* __restrict__ bm_p,
                          const float* __restrict__ bp_p,
                          const float* __restrict__ lap,
                          Accum* __restrict__ acc) {
    const float bm = bm_p[0], bp = bp_p[0];
    double pde = 0.0, bcs = 0.0, bcc = 0.0;
    const int stride = gridDim.x * blockDim.x;
    for (int i = blockIdx.x * blockDim.x + threadIdx.x; i < N_NODES; i += stride) {
        const float z    = x[4 * i + 3];
        const float beta = (z < 0.0f) ? bm : bp;
        const float res  = -lap[i] - source[i] / beta;
        pde += (double)(res * res);
        const float px = pos[2 * i], py = pos[2 * i + 1];
        if (fabsf(px) > 0.99f || fabsf(py) > 0.99f) {
            const float d = u_pred[i] - y[i];
            bcs += (double)(d * d);
            bcc += 1.0;
        }
    }
    double t = block_reduce(pde);
    if (threadIdx.x == 0) atomicAdd(&acc->pde_sum, t);
    t = block_reduce(bcs);
    if (threadIdx.x == 0) atomicAdd(&acc->bc_sum, t);
    t = block_reduce(bcc);
    if (threadIdx.x == 0) atomicAdd(&acc->bc_cnt, t);
}

// Pass 2 over edges: flux-jump loss (needs completed dx/dy).
__global__ void edge_pass2(const float* __restrict__ x,
                           const float* __restrict__ pos,
                           const int* __restrict__ row_idx,
                           const int* __restrict__ col_idx,
                           const int* __restrict__ eattr,
                           const float* __restrict__ dx,
                           const float* __restrict__ dy,
                           const float* __restrict__ a_p,
                           const float* __restrict__ b_p,
                           const float* __restrict__ c_p,
                           const float* __restrict__ bm_p,
                           const float* __restrict__ bp_p,
                           Accum* __restrict__ acc) {
    const float a = a_p[0], b = b_p[0], c = c_p[0], bm = bm_p[0], bp = bp_p[0];
    const float inva2 = 1.0f / (a * a), invb2 = 1.0f / (b * b);
    const float tgt_coef = 2.0f * (c * bp - bm);
    double j2s = 0.0;
    const int stride = gridDim.x * blockDim.x;
    for (int e = blockIdx.x * blockDim.x + threadIdx.x; e < N_EDGES; e += stride) {
        if (eattr[e] != 1) continue;
        const int r = row_idx[e];
        const int cc = col_idx[e];
        const float pmx = 0.5f * (pos[2 * r]     + pos[2 * cc]);
        const float pmy = 0.5f * (pos[2 * r + 1] + pos[2 * cc + 1]);
        const float nx = pmx * inva2, ny = pmy * invb2;
        const float nrm = fmaxf(sqrtf(nx * nx + ny * ny), kEPS);
        const float nxu = nx / nrm, nyu = ny / nrm;
        const float zs = x[4 * r + 3], zd = x[4 * cc + 3];
        const float beta_s = (zs < 0.0f) ? bm : bp;
        const float beta_d = (zd < 0.0f) ? bm : bp;
        const float sgn = (float)(zd > 0.0f) - (float)(zd < 0.0f);
        const float dn_s = dx[r]  * nxu + dy[r]  * nyu;
        const float dn_d = dx[cc] * nxu + dy[cc] * nyu;
        const float flux = sgn * (beta_d * dn_d - beta_s * dn_s);
        const float d = flux - tgt_coef * nrm;
        j2s += (double)(d * d);
    }
    double t = block_reduce(j2s);
    if (threadIdx.x == 0) atomicAdd(&acc->j2_sum, t);
}

__global__ void finalize(const Accum* __restrict__ acc, float* __restrict__ out) {
    if (threadIdx.x == 0 && blockIdx.x == 0) {
        const double loss_pde = acc->pde_sum / (double)N_NODES;
        const double loss_bc  = acc->bc_sum / fmax(acc->bc_cnt, 1.0);
        const double hc       = fmax(acc->het_cnt, 1.0);
        const double loss_j1  = acc->j1_sum / hc;
        const double loss_j2  = acc->j2_sum / hc;
        out[0] = (float)(1.0 * loss_pde + 100.0 * loss_bc + 10.0 * loss_j1 + 10.0 * loss_j2);
    }
}

extern "C" void kernel_launch(void* const* d_in, const int* in_sizes, int n_in,
                              void* d_out, int out_size, void* d_ws, size_t ws_size,
                              hipStream_t stream) {
    const float* u_pred = (const float*)d_in[0];
    const float* x      = (const float*)d_in[1];
    const float* pos    = (const float*)d_in[2];
    const float* y      = (const float*)d_in[3];
    const float* source = (const float*)d_in[4];
    const float* j1     = (const float*)d_in[5];
    const float* cdx    = (const float*)d_in[6];
    const float* cdy    = (const float*)d_in[7];
    const float* clap   = (const float*)d_in[8];
    const float* a_p    = (const float*)d_in[9];
    const float* b_p    = (const float*)d_in[10];
    const float* c_p    = (const float*)d_in[11];
    const float* bm_p   = (const float*)d_in[12];
    const float* bp_p   = (const float*)d_in[13];
    const int* edge_index = (const int*)d_in[14];
    const int* eattr      = (const int*)d_in[15];
    const int* row_idx = edge_index;
    const int* col_idx = edge_index + N_EDGES;

    float* dx  = (float*)d_ws;
    float* dy  = dx + N_NODES;
    float* lap = dy + N_NODES;
    Accum* acc = (Accum*)((char*)d_ws + (size_t)3 * N_NODES * sizeof(float));

    // zero segment arrays + accumulators (ws is NOT re-poisoned between replays)
    hipMemsetAsync(d_ws, 0, (size_t)3 * N_NODES * sizeof(float) + sizeof(Accum), stream);

    const int threads = 256;
    const int eblocks = 2048;
    const int nblocks = (N_NODES + threads - 1) / threads;

    edge_pass1<<<eblocks, threads, 0, stream>>>(u_pred, x, j1, cdx, cdy, clap,
                                                row_idx, col_idx, eattr,
                                                dx, dy, lap, acc);
    node_pass<<<nblocks, threads, 0, stream>>>(u_pred, x, pos, y, source,
                                               bm_p, bp_p, lap, acc);
    edge_pass2<<<eblocks, threads, 0, stream>>>(x, pos, row_idx, col_idx, eattr,
                                                dx, dy, a_p, b_p, c_p, bm_p, bp_p, acc);
    finalize<<<1, 64, 0, stream>>>(acc, (float*)d_out);
}